// Round 11
// baseline (261.155 us; speedup 1.0000x reference)
//
#include <hip/hip_runtime.h>
#include <hip/hip_bf16.h>
#include <cfloat>

#define B_   2
#define NQ_  1024
#define NK_  2048
#define H_   16
#define HD_  64
#define VPAD 2176      // vpT row stride in bf16 elements
#define GPAD 2112      // dmask row stride in bf16 elements

typedef float  floatx4 __attribute__((ext_vector_type(4)));
typedef __bf16 bf16x8  __attribute__((ext_vector_type(8)));
typedef __bf16 bf16x4  __attribute__((ext_vector_type(4)));

static __device__ __forceinline__ floatx4 mfma16(bf16x8 a, bf16x8 b, floatx4 c) {
    return __builtin_amdgcn_mfma_f32_16x16x32_bf16(a, b, c, 0, 0, 0);
}

// global -> LDS direct copy, 16B per lane. lbase wave-uniform.
static __device__ __forceinline__ void gl_lds(const __bf16* g, __bf16* lbase,
                                              int lane) {
#if __has_builtin(__builtin_amdgcn_global_load_lds)
    __builtin_amdgcn_global_load_lds(
        (const __attribute__((address_space(1))) void*)g,
        (__attribute__((address_space(3))) void*)lbase, 16, 0, 0);
#else
    *(bf16x8*)(lbase + lane * 8) = *(const bf16x8*)g;
#endif
}

// ---------------------------------------------------------------------------
// Kernel 0: fused f32->bf16 conversion (blocks 0..1791, 4 groups/thread) +
// per-batch masked distance sum AND masked-d bf16 emit (blocks 1792..2815).
// dmask[b][q][k] = masked ? d : 3e38 (sentinel; attn's c<0 turns it into 0)
// ---------------------------------------------------------------------------
struct CvtArgs {
    const float* src[7];
    __bf16*      dst[7];
};

__global__ __launch_bounds__(256) void cvt_mean_kernel(
    CvtArgs a, const float* __restrict__ dist, const int* __restrict__ amask,
    const int* __restrict__ kpmk, float* __restrict__ msum,
    __bf16* __restrict__ dmask)
{
    if (blockIdx.x >= 1792) {
        const int mb = blockIdx.x - 1792;      // 0..1023
        const int b  = mb >> 9;                // 0..1
        const float* d  = dist  + (size_t)b * NQ_ * NK_;
        const int*   am = amask + (size_t)b * NQ_ * NK_;
        const int*   km = kpmk  + b * NK_;
        __bf16*      dm = dmask + (size_t)b * NQ_ * GPAD;
        const int base = (mb & 511) * 256 + threadIdx.x;   // 0..131071
        float s = 0.f;
        #pragma unroll
        for (int j = 0; j < 4; j++) {
            const int i   = base + j * 131072;
            const int idx = i * 4;
            const int kk  = idx & (NK_ - 1);
            const int q   = i >> 9;
            float4 dv = *(const float4*)(d + idx);
            int4   mv = *(const int4*)(am + idx);
            int4   kv = *(const int4*)(km + kk);
            bf16x4 o;
            if (mv.x && kv.x) { s += dv.x; o[0] = (__bf16)dv.x; } else o[0] = (__bf16)3e38f;
            if (mv.y && kv.y) { s += dv.y; o[1] = (__bf16)dv.y; } else o[1] = (__bf16)3e38f;
            if (mv.z && kv.z) { s += dv.z; o[2] = (__bf16)dv.z; } else o[2] = (__bf16)3e38f;
            if (mv.w && kv.w) { s += dv.w; o[3] = (__bf16)dv.w; } else o[3] = (__bf16)3e38f;
            *(bf16x4*)&dm[(size_t)q * GPAD + kk] = o;
        }
        #pragma unroll
        for (int off = 32; off >= 1; off >>= 1) s += __shfl_down(s, off);
        __shared__ float wsum[4];
        if ((threadIdx.x & 63) == 0) wsum[threadIdx.x >> 6] = s;
        __syncthreads();
        if (threadIdx.x == 0)
            atomicAdd(&msum[b], wsum[0] + wsum[1] + wsum[2] + wsum[3]);
        return;
    }
    // cvt part: 1792 blocks x 256 threads x 4 groups = 1835008 groups of 8
    #pragma unroll
    for (int j = 0; j < 4; j++) {
        size_t r = (size_t)blockIdx.x * 1024 + j * 256 + threadIdx.x;
        int s;
        if (r < 262144)                  { s = 0; }
        else if ((r -= 262144) < 524288) { s = 1; }
        else if ((r -= 524288) < 524288) { s = 2; }
        else { r -= 524288; s = 3 + (int)(r >> 17); r &= 131071; }
        const float* sp = a.src[s] + r * 8;
        float4 f0 = *(const float4*)sp;
        float4 f1 = *(const float4*)(sp + 4);
        bf16x8 o;
        o[0] = (__bf16)f0.x; o[1] = (__bf16)f0.y; o[2] = (__bf16)f0.z; o[3] = (__bf16)f0.w;
        o[4] = (__bf16)f1.x; o[5] = (__bf16)f1.y; o[6] = (__bf16)f1.z; o[7] = (__bf16)f1.w;
        *(bf16x8*)(a.dst[s] + r * 8) = o;
    }
}

// ---------------------------------------------------------------------------
// m97-style GEMM core, BK=64 as two BK=32 halves per barrier pair.
// 128x128 tile, 256 threads (2x2 waves of 64x64), global_load_lds width=16.
// LDS buffers passed in (declared ONCE per kernel).
// ---------------------------------------------------------------------------
template <typename EPI>
static __device__ __forceinline__ void gemm128_core(
    const __bf16* __restrict__ A, const __bf16* __restrict__ Bw,
    int m0, int n0, __bf16* As, __bf16* Bs, EPI epi)
{
    const int t    = threadIdx.x;
    const int w    = t >> 6, lane = t & 63;
    const int lrow = lane & 15, quad = lane >> 4;
    const int lr   = lane >> 2, lc = lane & 3;   // 16 rows x 4 16B-chunks

    floatx4 acc[4][4];
    #pragma unroll
    for (int mi = 0; mi < 4; mi++)
        #pragma unroll
        for (int ni = 0; ni < 4; ni++) acc[mi][ni] = floatx4{0.f, 0.f, 0.f, 0.f};

    const __bf16* ga = A  + (size_t)(m0 + w * 32 + lr) * 1024 + lc * 8;
    const __bf16* gb = Bw + (size_t)(n0 + w * 32 + lr) * 1024 + lc * 8;

    for (int k0 = 0; k0 < 1024; k0 += 64) {
        __syncthreads();
        #pragma unroll
        for (int h = 0; h < 2; h++) {
            gl_lds(ga + k0 + h * 32,             &As[h * 4096 + (w * 32) * 32],      lane);
            gl_lds(ga + k0 + h * 32 + 16 * 1024, &As[h * 4096 + (w * 32 + 16) * 32], lane);
            gl_lds(gb + k0 + h * 32,             &Bs[h * 4096 + (w * 32) * 32],      lane);
            gl_lds(gb + k0 + h * 32 + 16 * 1024, &Bs[h * 4096 + (w * 32 + 16) * 32], lane);
        }
        __syncthreads();

        #pragma unroll
        for (int h = 0; h < 2; h++) {
            bf16x8 af[4], bfr[4];
            #pragma unroll
            for (int mi = 0; mi < 4; mi++)
                af[mi] = *(const bf16x8*)
                    &As[h * 4096 + ((w & 1) * 64 + mi * 16 + lrow) * 32 + quad * 8];
            #pragma unroll
            for (int ni = 0; ni < 4; ni++)
                bfr[ni] = *(const bf16x8*)
                    &Bs[h * 4096 + ((w >> 1) * 64 + ni * 16 + lrow) * 32 + quad * 8];
            #pragma unroll
            for (int mi = 0; mi < 4; mi++)
                #pragma unroll
                for (int ni = 0; ni < 4; ni++)
                    acc[mi][ni] = mfma16(af[mi], bfr[ni], acc[mi][ni]);
        }
    }

    #pragma unroll
    for (int mi = 0; mi < 4; mi++)
        #pragma unroll
        for (int ni = 0; ni < 4; ni++)
            #pragma unroll
            for (int r = 0; r < 4; r++) {
                const int m = m0 + (w & 1) * 64 + mi * 16 + quad * 4 + r;
                const int n = n0 + (w >> 1) * 64 + ni * 16 + lrow;
                epi(m, n, acc[mi][ni][r]);
            }
}

// 64x128-tile variant for the small oproj GEMM (fills 256 blocks).
template <typename EPI>
static __device__ __forceinline__ void gemm64_core(
    const __bf16* __restrict__ A, const __bf16* __restrict__ Bw,
    int m0, int n0, EPI epi)
{
    __shared__ alignas(16) __bf16 As[2][64 * 32];
    __shared__ alignas(16) __bf16 Bs[2][128 * 32];
    const int t    = threadIdx.x;
    const int w    = t >> 6, lane = t & 63;
    const int lrow = lane & 15, quad = lane >> 4;
    const int lr   = lane >> 2, lc = lane & 3;

    floatx4 acc[4][2];
    #pragma unroll
    for (int mi = 0; mi < 4; mi++)
        #pragma unroll
        for (int ni = 0; ni < 2; ni++) acc[mi][ni] = floatx4{0.f, 0.f, 0.f, 0.f};

    const __bf16* ga = A  + (size_t)(m0 + w * 16 + lr) * 1024 + lc * 8;
    const __bf16* gb = Bw + (size_t)(n0 + w * 32 + lr) * 1024 + lc * 8;

    for (int k0 = 0; k0 < 1024; k0 += 64) {
        __syncthreads();
        #pragma unroll
        for (int h = 0; h < 2; h++) {
            gl_lds(ga + k0 + h * 32,             &As[h][(w * 16) * 32],      lane);
            gl_lds(gb + k0 + h * 32,             &Bs[h][(w * 32) * 32],      lane);
            gl_lds(gb + k0 + h * 32 + 16 * 1024, &Bs[h][(w * 32 + 16) * 32], lane);
        }
        __syncthreads();

        #pragma unroll
        for (int h = 0; h < 2; h++) {
            bf16x8 af[4], bfr[2];
            #pragma unroll
            for (int mi = 0; mi < 4; mi++)
                af[mi] = *(const bf16x8*)
                    &As[h][(mi * 16 + lrow) * 32 + quad * 8];
            #pragma unroll
            for (int ni = 0; ni < 2; ni++)
                bfr[ni] = *(const bf16x8*)
                    &Bs[h][(w * 32 + ni * 16 + lrow) * 32 + quad * 8];
            #pragma unroll
            for (int mi = 0; mi < 4; mi++)
                #pragma unroll
                for (int ni = 0; ni < 2; ni++)
                    acc[mi][ni] = mfma16(af[mi], bfr[ni], acc[mi][ni]);
        }
    }

    #pragma unroll
    for (int mi = 0; mi < 4; mi++)
        #pragma unroll
        for (int ni = 0; ni < 2; ni++)
            #pragma unroll
            for (int r = 0; r < 4; r++) {
                const int m = m0 + mi * 16 + quad * 4 + r;
                const int n = n0 + w * 32 + ni * 16 + lrow;
                epi(m, n, acc[mi][ni][r]);
            }
}

// Fused projection kernel: z = 0 -> qp, 1 -> kp, 2 -> vpT (operand-swapped).
__global__ __launch_bounds__(256) void proj_kernel(
    const __bf16* __restrict__ qb, const __bf16* __restrict__ kb,
    const __bf16* __restrict__ vb, const __bf16* __restrict__ wqb,
    const __bf16* __restrict__ wkb, const __bf16* __restrict__ wvb,
    __bf16* __restrict__ qp, __bf16* __restrict__ kp,
    __bf16* __restrict__ vpT)
{
    __shared__ alignas(16) __bf16 As[2 * 128 * 32];
    __shared__ alignas(16) __bf16 Bs[2 * 128 * 32];
    const int z = blockIdx.z;
    if (z == 0) {
        if ((int)blockIdx.x >= 16) return;
        gemm128_core(qb, wqb, blockIdx.x * 128, blockIdx.y * 128, As, Bs,
                     [&](int m, int n, float v) {
            const int b = m >> 10, q = m & 1023;
            const int h = n >> 6,  d = n & 63;
            qp[(((size_t)(b * 16 + h) * NQ_ + q) << 6) + d] = (__bf16)v;
        });
    } else if (z == 1) {
        gemm128_core(kb, wkb, blockIdx.x * 128, blockIdx.y * 128, As, Bs,
                     [&](int m, int n, float v) {
            const int b = m >> 11, key = m & 2047;
            const int h = n >> 6,  d = n & 63;
            kp[(((size_t)(b * 16 + h) * NK_ + key) << 6) + d] = (__bf16)v;
        });
    } else {
        // swapped: A = Wv (rows = hd), B = V (rows = keys)
        gemm128_core(wvb, vb, blockIdx.y * 128, blockIdx.x * 128, As, Bs,
                     [&](int m, int n, float v) {
            const int h = m >> 6,  d = m & 63;
            const int b = n >> 11, key = n & 2047;
            vpT[((size_t)(b * 16 + h) * HD_ + d) * VPAD + key] = (__bf16)v;
        });
    }
}

// Output projection: attnout(2048x1024 bf16) x Wo^T -> d_out f32
__global__ __launch_bounds__(256) void oproj_kernel(
    const __bf16* __restrict__ A, const __bf16* __restrict__ W,
    float* __restrict__ Cout)
{
    const int m0 = blockIdx.x * 64, n0 = blockIdx.y * 128;
    gemm64_core(A, W, m0, n0, [&](int m, int n, float v) {
        Cout[(size_t)m * 1024 + n] = v;
    });
}

// ---------------------------------------------------------------------------
// Fused attention, in-block split-K, 32 q per wave (2 q-groups sharing every
// K/V fragment read -> 2x LDS-read amortization vs R10). Block = 8 waves
// (512 thr) = 2 key-groups x 4 waves; each group stages its own K/V tiles.
// Grid (8,32) = 256 blocks = exactly 1 block/CU (zero tail). In-block
// combine: group 1 dumps O+G into LDS (aliased over Ps), group 0 adds,
// normalizes by complete G, applies kpm_q, writes attnout bf16.
// Gate folded into exponent: eg = exp(s/8 + c*d), masked d=3e38 -> 0.
// ---------------------------------------------------------------------------
__global__ __launch_bounds__(512, 2) void attn_kernel(
    const __bf16* __restrict__ qp, const __bf16* __restrict__ kp,
    const __bf16* __restrict__ vpT, const __bf16* __restrict__ dmask,
    const float* __restrict__ msum, const float* __restrict__ galpha,
    const int* __restrict__ kpmq, __bf16* __restrict__ attnout)
{
    __shared__ __bf16 Ks[2][64 * 72];                 // per key-group
    __shared__ __bf16 Vt[2][64 * 72];                 // per key-group
    __shared__ alignas(16) char PsOx[8 * 32 * 72 * 2]; // Ps during loop; Ox after
    __shared__ float  Gx[4][32];
    const int t    = threadIdx.x;
    const int w    = t >> 6, lane = t & 63;
    const int g    = w >> 2;              // key-group 0/1
    const int wg   = w & 3;               // wave within group (q sub-tile)
    const int lrow = lane & 15, quad = lane >> 4;
    const int qt   = blockIdx.x;          // 0..7
    const int bh   = blockIdx.y;          // 0..31
    const int b    = bh >> 4, h = bh & 15;
    const int q0   = qt * 128 + wg * 32;
    const int k0   = g * (NK_ / 2);
    const int NT   = (NK_ / 2) / 64;      // 16 tiles per group

    __bf16* Ps = (__bf16*)PsOx + w * 32 * 72;           // per-wave P tile
    float (*Ox)[32][68] = (float (*)[32][68])PsOx;      // [wg][q][hd] exchange

    const float mean  = fmaxf(msum[b] / ((float)(NQ_ * NK_) + 1e-6f), 1e-6f);
    const float alpha = log1pf(__expf(galpha[0]));
    const float cg    = -alpha / mean;    // strictly negative

    bf16x8 qf[2][2];
    #pragma unroll
    for (int qg = 0; qg < 2; qg++) {
        const __bf16* qb = qp + ((size_t)bh * NQ_ + q0 + qg * 16 + lrow) * HD_ +
                           quad * 8;
        qf[qg][0] = *(const bf16x8*)qb;
        qf[qg][1] = *(const bf16x8*)(qb + 32);
    }

    const int tg    = t & 255;            // thread index within key-group
    const int srow0 = tg >> 3,        sc0 = tg & 7;
    const int srow1 = 32 + (tg >> 3), sc1 = tg & 7;
    const int so0 = srow0 * 72 + sc0 * 8;
    const int so1 = srow1 * 72 + sc1 * 8;
    const __bf16* Kg = kp  + (size_t)bh * NK_ * HD_;
    const __bf16* Vg = vpT + (size_t)bh * HD_ * VPAD;

    const __bf16* grow[2];
    #pragma unroll
    for (int qg = 0; qg < 2; qg++)
        grow[qg] = dmask + ((size_t)b * NQ_ + q0 + qg * 16 + lrow) * GPAD;

    float G[2] = {0.f, 0.f};
    floatx4 O[2][4];
    #pragma unroll
    for (int qg = 0; qg < 2; qg++)
        #pragma unroll
        for (int nb = 0; nb < 4; nb++) O[qg][nb] = floatx4{0.f, 0.f, 0.f, 0.f};

    bf16x8 kr0, kr1, vr0, vr1;
    bf16x4 gr[2][4];
    auto loadt = [&](int kb) {
        kr0 = *(const bf16x8*)(Kg + (size_t)(kb + srow0) * HD_ + sc0 * 8);
        kr1 = *(const bf16x8*)(Kg + (size_t)(kb + srow1) * HD_ + sc1 * 8);
        vr0 = *(const bf16x8*)(Vg + (size_t)srow0 * VPAD + kb + sc0 * 8);
        vr1 = *(const bf16x8*)(Vg + (size_t)srow1 * VPAD + kb + sc1 * 8);
        #pragma unroll
        for (int qg = 0; qg < 2; qg++)
            #pragma unroll
            for (int c = 0; c < 4; c++)
                gr[qg][c] = *(const bf16x4*)(grow[qg] + kb + c * 16 + quad * 4);
    };
    loadt(k0);

    for (int ib = 0; ib < NT; ib++) {
        const int kb = k0 + ib * 64;

        __syncthreads();                  // prior tile's LDS reads complete
        *(bf16x8*)&Ks[g][so0] = kr0;
        *(bf16x8*)&Ks[g][so1] = kr1;
        *(bf16x8*)&Vt[g][so0] = vr0;
        *(bf16x8*)&Vt[g][so1] = vr1;
        __syncthreads();                  // staging visible

        bf16x4 gcur[2][4];
        #pragma unroll
        for (int qg = 0; qg < 2; qg++)
            #pragma unroll
            for (int c = 0; c < 4; c++) gcur[qg][c] = gr[qg][c];
        if (ib + 1 < NT) loadt(kb + 64);

        // --- QK: K-fragments loaded once, used for both q-groups ---
        floatx4 s4[2][4];
        #pragma unroll
        for (int c = 0; c < 4; c++) {
            bf16x8 kf0 = *(const bf16x8*)&Ks[g][(c * 16 + lrow) * 72 + quad * 8];
            bf16x8 kf1 = *(const bf16x8*)&Ks[g][(c * 16 + lrow) * 72 + 32 + quad * 8];
            #pragma unroll
            for (int qg = 0; qg < 2; qg++) {
                floatx4 a = floatx4{0.f, 0.f, 0.f, 0.f};
                a = mfma16(kf0, qf[qg][0], a);
                a = mfma16(kf1, qf[qg][1], a);
                s4[qg][c] = a;
            }
        }

        // --- exp: eg = exp(s/8 + c*d) -> Ps ---
        #pragma unroll
        for (int qg = 0; qg < 2; qg++) {
            #pragma unroll
            for (int c = 0; c < 4; c++) {
                const float e0 = __expf(fmaf(s4[qg][c][0], 0.125f, cg * (float)gcur[qg][c][0]));
                const float e1 = __expf(fmaf(s4[qg][c][1], 0.125f, cg * (float)gcur[qg][c][1]));
                const float e2 = __expf(fmaf(s4[qg][c][2], 0.125f, cg * (float)gcur[qg][c][2]));
                const float e3 = __expf(fmaf(s4[qg][c][3], 0.125f, cg * (float)gcur[qg][c][3]));
                G[qg] += (e0 + e1) + (e2 + e3);
                bf16x4 pk;
                pk[0] = (__bf16)e0; pk[1] = (__bf16)e1;
                pk[2] = (__bf16)e2; pk[3] = (__bf16)e3;
                *(bf16x4*)&Ps[(qg * 16 + lrow) * 72 + c * 16 + quad * 4] = pk;
            }
        }

        // --- PV: V-fragments loaded once, used for both q-groups ---
        bf16x8 pf[2][2];
        #pragma unroll
        for (int qg = 0; qg < 2; qg++) {
            pf[qg][0] = *(const bf16x8*)&Ps[(qg * 16 + lrow) * 72 + quad * 8];
            pf[qg][1] = *(const bf16x8*)&Ps[(qg * 16 + lrow) * 72 + 32 + quad * 8];
        }
        #pragma unroll
        for (int tt = 0; tt < 2; tt++)
            #pragma unroll
            for (int nb = 0; nb < 4; nb++) {
                bf16x8 vf = *(const bf16x8*)
                    &Vt[g][(nb * 16 + lrow) * 72 + tt * 32 + quad * 8];
                #pragma unroll
                for (int qg = 0; qg < 2; qg++)
                    O[qg][nb] = mfma16(pf[qg][tt], vf, O[qg][nb]);
            }
    }

    // per-wave G reduce across quads
    #pragma unroll
    for (int qg = 0; qg < 2; qg++) {
        G[qg] += __shfl_xor(G[qg], 16);
        G[qg] += __shfl_xor(G[qg], 32);
    }

    // in-block combine: group 1 -> LDS (aliased over Ps), group 0 epilogue
    __syncthreads();                      // loop LDS reads complete
    if (g == 1) {
        #pragma unroll
        for (int qg = 0; qg < 2; qg++)
            #pragma unroll
            for (int nb = 0; nb < 4; nb++)
                #pragma unroll
                for (int r = 0; r < 4; r++)
                    Ox[wg][qg * 16 + quad * 4 + r][nb * 16 + lrow] = O[qg][nb][r];
        if (quad == 0) {
            #pragma unroll
            for (int qg = 0; qg < 2; qg++)
                Gx[wg][qg * 16 + lrow] = G[qg];
        }
    }
    __syncthreads();
    if (g == 0) {
        #pragma unroll
        for (int qg = 0; qg < 2; qg++) {
            #pragma unroll
            for (int r = 0; r < 4; r++) {
                const int j  = qg * 16 + quad * 4 + r;
                const int q  = q0 + j;
                const float gq = __shfl(G[qg], quad * 4 + r) + Gx[wg][j];
                const float f  = kpmq[b * NQ_ + q] ? 1.f / (gq + 1e-30f) : 0.f;
                #pragma unroll
                for (int nb = 0; nb < 4; nb++) {
                    const float ov = O[qg][nb][r] + Ox[wg][j][nb * 16 + lrow];
                    attnout[((size_t)b * NQ_ + q) * 1024 + h * HD_ + nb * 16 + lrow] =
                        (__bf16)(ov * f);
                }
            }
        }
    }
}

// ---------------------------------------------------------------------------
extern "C" void kernel_launch(void* const* d_in, const int* in_sizes, int n_in,
                              void* d_out, int out_size, void* d_ws,
                              size_t ws_size, hipStream_t stream)
{
    const float* q      = (const float*)d_in[0];
    const float* k      = (const float*)d_in[1];
    const float* v      = (const float*)d_in[2];
    const float* dist   = (const float*)d_in[3];
    const int*   amask  = (const int*)d_in[4];
    const int*   kpmq   = (const int*)d_in[5];
    const int*   kpmk   = (const int*)d_in[6];
    const float* Wq     = (const float*)d_in[7];
    const float* Wk     = (const float*)d_in[8];
    const float* Wv     = (const float*)d_in[9];
    const float* Wo     = (const float*)d_in[10];
    const float* galpha = (const float*)d_in[11];

    char* p = (char*)d_ws;
    float*  msum = (float*)p;                 p += 256;
    __bf16* qb   = (__bf16*)p;                p += (size_t)2097152 * 2;
    __bf16* kb   = (__bf16*)p;                p += (size_t)4194304 * 2;
    __bf16* vb   = (__bf16*)p;                p += (size_t)4194304 * 2;
    __bf16* wqb  = (__bf16*)p;                p += (size_t)1048576 * 2;
    __bf16* wkb  = (__bf16*)p;                p += (size_t)1048576 * 2;
    __bf16* wvb  = (__bf16*)p;                p += (size_t)1048576 * 2;
    __bf16* wob  = (__bf16*)p;                p += (size_t)1048576 * 2;
    __bf16* qp   = (__bf16*)p;                p += (size_t)2097152 * 2;
    __bf16* kpb  = (__bf16*)p;                p += (size_t)4194304 * 2;
    __bf16* vpT  = (__bf16*)p;                p += (size_t)32 * 64 * VPAD * 2;
    __bf16* dmask = (__bf16*)p;               p += (size_t)2048 * GPAD * 2;
    __bf16* attnout = (__bf16*)p;             p += (size_t)2097152 * 2;

    CvtArgs ca;
    ca.src[0] = q;  ca.src[1] = k;  ca.src[2] = v;
    ca.src[3] = Wq; ca.src[4] = Wk; ca.src[5] = Wv; ca.src[6] = Wo;
    ca.dst[0] = qb;  ca.dst[1] = kb;  ca.dst[2] = vb;
    ca.dst[3] = wqb; ca.dst[4] = wkb; ca.dst[5] = wvb; ca.dst[6] = wob;

    hipMemsetAsync(msum, 0, 256, stream);
    cvt_mean_kernel<<<2816, 256, 0, stream>>>(ca, dist, amask, kpmk, msum,
                                              dmask);
    proj_kernel<<<dim3(32, 8, 3), 256, 0, stream>>>(qb, kb, vb, wqb, wkb, wvb,
                                                    qp, kpb, vpT);
    attn_kernel<<<dim3(8, 32), 512, 0, stream>>>(qp, kpb, vpT, dmask,
                                                 msum, galpha, kpmq, attnout);
    oproj_kernel<<<dim3(32, 8), 256, 0, stream>>>(attnout, wob, (float*)d_out);
}

// Round 12
// 242.837 us; speedup vs baseline: 1.0754x; 1.0754x over previous
//
#include <hip/hip_runtime.h>
#include <hip/hip_bf16.h>
#include <cfloat>

#define B_   2
#define NQ_  1024
#define NK_  2048
#define H_   16
#define HD_  64
#define VPAD 2176      // vpT row stride in bf16 elements
#define GPAD 2112      // dmask row stride in bf16 elements

typedef float  floatx4 __attribute__((ext_vector_type(4)));
typedef __bf16 bf16x8  __attribute__((ext_vector_type(8)));
typedef __bf16 bf16x4  __attribute__((ext_vector_type(4)));

static __device__ __forceinline__ floatx4 mfma16(bf16x8 a, bf16x8 b, floatx4 c) {
    return __builtin_amdgcn_mfma_f32_16x16x32_bf16(a, b, c, 0, 0, 0);
}

// global -> LDS direct copy, 16B per lane. lbase wave-uniform.
static __device__ __forceinline__ void gl_lds(const __bf16* g, __bf16* lbase,
                                              int lane) {
#if __has_builtin(__builtin_amdgcn_global_load_lds)
    __builtin_amdgcn_global_load_lds(
        (const __attribute__((address_space(1))) void*)g,
        (__attribute__((address_space(3))) void*)lbase, 16, 0, 0);
#else
    *(bf16x8*)(lbase + lane * 8) = *(const bf16x8*)g;
#endif
}

// ---------------------------------------------------------------------------
// Kernel 0: fused f32->bf16 conversion (blocks 0..1791, 4 groups/thread) +
// per-batch masked distance sum AND masked-d bf16 emit (blocks 1792..2815).
// dmask[b][q][k] = masked ? d : 3e38 (sentinel; attn's c<0 turns it into 0)
// ---------------------------------------------------------------------------
struct CvtArgs {
    const float* src[7];
    __bf16*      dst[7];
};

__global__ __launch_bounds__(256) void cvt_mean_kernel(
    CvtArgs a, const float* __restrict__ dist, const int* __restrict__ amask,
    const int* __restrict__ kpmk, float* __restrict__ msum,
    __bf16* __restrict__ dmask)
{
    if (blockIdx.x >= 1792) {
        const int mb = blockIdx.x - 1792;      // 0..1023
        const int b  = mb >> 9;                // 0..1
        const float* d  = dist  + (size_t)b * NQ_ * NK_;
        const int*   am = amask + (size_t)b * NQ_ * NK_;
        const int*   km = kpmk  + b * NK_;
        __bf16*      dm = dmask + (size_t)b * NQ_ * GPAD;
        const int base = (mb & 511) * 256 + threadIdx.x;   // 0..131071
        float s = 0.f;
        #pragma unroll
        for (int j = 0; j < 4; j++) {
            const int i   = base + j * 131072;
            const int idx = i * 4;
            const int kk  = idx & (NK_ - 1);
            const int q   = i >> 9;
            float4 dv = *(const float4*)(d + idx);
            int4   mv = *(const int4*)(am + idx);
            int4   kv = *(const int4*)(km + kk);
            bf16x4 o;
            if (mv.x && kv.x) { s += dv.x; o[0] = (__bf16)dv.x; } else o[0] = (__bf16)3e38f;
            if (mv.y && kv.y) { s += dv.y; o[1] = (__bf16)dv.y; } else o[1] = (__bf16)3e38f;
            if (mv.z && kv.z) { s += dv.z; o[2] = (__bf16)dv.z; } else o[2] = (__bf16)3e38f;
            if (mv.w && kv.w) { s += dv.w; o[3] = (__bf16)dv.w; } else o[3] = (__bf16)3e38f;
            *(bf16x4*)&dm[(size_t)q * GPAD + kk] = o;
        }
        #pragma unroll
        for (int off = 32; off >= 1; off >>= 1) s += __shfl_down(s, off);
        __shared__ float wsum[4];
        if ((threadIdx.x & 63) == 0) wsum[threadIdx.x >> 6] = s;
        __syncthreads();
        if (threadIdx.x == 0)
            atomicAdd(&msum[b], wsum[0] + wsum[1] + wsum[2] + wsum[3]);
        return;
    }
    // cvt part: 1792 blocks x 256 threads x 4 groups = 1835008 groups of 8
    #pragma unroll
    for (int j = 0; j < 4; j++) {
        size_t r = (size_t)blockIdx.x * 1024 + j * 256 + threadIdx.x;
        int s;
        if (r < 262144)                  { s = 0; }
        else if ((r -= 262144) < 524288) { s = 1; }
        else if ((r -= 524288) < 524288) { s = 2; }
        else { r -= 524288; s = 3 + (int)(r >> 17); r &= 131071; }
        const float* sp = a.src[s] + r * 8;
        float4 f0 = *(const float4*)sp;
        float4 f1 = *(const float4*)(sp + 4);
        bf16x8 o;
        o[0] = (__bf16)f0.x; o[1] = (__bf16)f0.y; o[2] = (__bf16)f0.z; o[3] = (__bf16)f0.w;
        o[4] = (__bf16)f1.x; o[5] = (__bf16)f1.y; o[6] = (__bf16)f1.z; o[7] = (__bf16)f1.w;
        *(bf16x8*)(a.dst[s] + r * 8) = o;
    }
}

// ---------------------------------------------------------------------------
// m97-style GEMM core, BK=64 as two BK=32 halves per barrier pair.
// 128x128 tile, 256 threads (2x2 waves of 64x64), global_load_lds width=16.
// LDS buffers passed in (declared ONCE per kernel).
// ---------------------------------------------------------------------------
template <typename EPI>
static __device__ __forceinline__ void gemm128_core(
    const __bf16* __restrict__ A, const __bf16* __restrict__ Bw,
    int m0, int n0, __bf16* As, __bf16* Bs, EPI epi)
{
    const int t    = threadIdx.x;
    const int w    = t >> 6, lane = t & 63;
    const int lrow = lane & 15, quad = lane >> 4;
    const int lr   = lane >> 2, lc = lane & 3;   // 16 rows x 4 16B-chunks

    floatx4 acc[4][4];
    #pragma unroll
    for (int mi = 0; mi < 4; mi++)
        #pragma unroll
        for (int ni = 0; ni < 4; ni++) acc[mi][ni] = floatx4{0.f, 0.f, 0.f, 0.f};

    const __bf16* ga = A  + (size_t)(m0 + w * 32 + lr) * 1024 + lc * 8;
    const __bf16* gb = Bw + (size_t)(n0 + w * 32 + lr) * 1024 + lc * 8;

    for (int k0 = 0; k0 < 1024; k0 += 64) {
        __syncthreads();
        #pragma unroll
        for (int h = 0; h < 2; h++) {
            gl_lds(ga + k0 + h * 32,             &As[h * 4096 + (w * 32) * 32],      lane);
            gl_lds(ga + k0 + h * 32 + 16 * 1024, &As[h * 4096 + (w * 32 + 16) * 32], lane);
            gl_lds(gb + k0 + h * 32,             &Bs[h * 4096 + (w * 32) * 32],      lane);
            gl_lds(gb + k0 + h * 32 + 16 * 1024, &Bs[h * 4096 + (w * 32 + 16) * 32], lane);
        }
        __syncthreads();

        #pragma unroll
        for (int h = 0; h < 2; h++) {
            bf16x8 af[4], bfr[4];
            #pragma unroll
            for (int mi = 0; mi < 4; mi++)
                af[mi] = *(const bf16x8*)
                    &As[h * 4096 + ((w & 1) * 64 + mi * 16 + lrow) * 32 + quad * 8];
            #pragma unroll
            for (int ni = 0; ni < 4; ni++)
                bfr[ni] = *(const bf16x8*)
                    &Bs[h * 4096 + ((w >> 1) * 64 + ni * 16 + lrow) * 32 + quad * 8];
            #pragma unroll
            for (int mi = 0; mi < 4; mi++)
                #pragma unroll
                for (int ni = 0; ni < 4; ni++)
                    acc[mi][ni] = mfma16(af[mi], bfr[ni], acc[mi][ni]);
        }
    }

    #pragma unroll
    for (int mi = 0; mi < 4; mi++)
        #pragma unroll
        for (int ni = 0; ni < 4; ni++)
            #pragma unroll
            for (int r = 0; r < 4; r++) {
                const int m = m0 + (w & 1) * 64 + mi * 16 + quad * 4 + r;
                const int n = n0 + (w >> 1) * 64 + ni * 16 + lrow;
                epi(m, n, acc[mi][ni][r]);
            }
}

// 32x128-tile variant for oproj: grid (64,8) = 512 blocks = 2 blocks/CU
// (the old 64x128 at 256 blocks was 1 block/CU, 1 wave/SIMD — every
// barrier/vmcnt drain fully exposed; R11 showed that mode is toxic).
template <typename EPI>
static __device__ __forceinline__ void gemm32_core(
    const __bf16* __restrict__ A, const __bf16* __restrict__ Bw,
    int m0, int n0, EPI epi)
{
    __shared__ alignas(16) __bf16 As[2][32 * 32];
    __shared__ alignas(16) __bf16 Bs[2][128 * 32];
    const int t    = threadIdx.x;
    const int w    = t >> 6, lane = t & 63;
    const int lrow = lane & 15, quad = lane >> 4;
    const int lr   = lane >> 2, lc = lane & 3;

    floatx4 acc[2][2];
    #pragma unroll
    for (int mi = 0; mi < 2; mi++)
        #pragma unroll
        for (int ni = 0; ni < 2; ni++) acc[mi][ni] = floatx4{0.f, 0.f, 0.f, 0.f};

    const __bf16* ga = A  + (size_t)(m0 + (w & 1) * 16 + lr) * 1024 + lc * 8;
    const __bf16* gb = Bw + (size_t)(n0 + w * 32 + lr) * 1024 + lc * 8;

    for (int k0 = 0; k0 < 1024; k0 += 64) {
        __syncthreads();
        #pragma unroll
        for (int h = 0; h < 2; h++) {
            if (w < 2)
                gl_lds(ga + k0 + h * 32, &As[h][(w * 16) * 32], lane);
            gl_lds(gb + k0 + h * 32,             &Bs[h][(w * 32) * 32],      lane);
            gl_lds(gb + k0 + h * 32 + 16 * 1024, &Bs[h][(w * 32 + 16) * 32], lane);
        }
        __syncthreads();

        #pragma unroll
        for (int h = 0; h < 2; h++) {
            bf16x8 af[2], bfr[2];
            #pragma unroll
            for (int mi = 0; mi < 2; mi++)
                af[mi] = *(const bf16x8*)
                    &As[h][(mi * 16 + lrow) * 32 + quad * 8];
            #pragma unroll
            for (int ni = 0; ni < 2; ni++)
                bfr[ni] = *(const bf16x8*)
                    &Bs[h][(w * 32 + ni * 16 + lrow) * 32 + quad * 8];
            #pragma unroll
            for (int mi = 0; mi < 2; mi++)
                #pragma unroll
                for (int ni = 0; ni < 2; ni++)
                    acc[mi][ni] = mfma16(af[mi], bfr[ni], acc[mi][ni]);
        }
    }

    #pragma unroll
    for (int mi = 0; mi < 2; mi++)
        #pragma unroll
        for (int ni = 0; ni < 2; ni++)
            #pragma unroll
            for (int r = 0; r < 4; r++) {
                const int m = m0 + mi * 16 + quad * 4 + r;
                const int n = n0 + w * 32 + ni * 16 + lrow;
                epi(m, n, acc[mi][ni][r]);
            }
}

// Fused projection kernel: z = 0 -> qp, 1 -> kp, 2 -> vpT (operand-swapped).
__global__ __launch_bounds__(256) void proj_kernel(
    const __bf16* __restrict__ qb, const __bf16* __restrict__ kb,
    const __bf16* __restrict__ vb, const __bf16* __restrict__ wqb,
    const __bf16* __restrict__ wkb, const __bf16* __restrict__ wvb,
    __bf16* __restrict__ qp, __bf16* __restrict__ kp,
    __bf16* __restrict__ vpT)
{
    __shared__ alignas(16) __bf16 As[2 * 128 * 32];
    __shared__ alignas(16) __bf16 Bs[2 * 128 * 32];
    const int z = blockIdx.z;
    if (z == 0) {
        if ((int)blockIdx.x >= 16) return;
        gemm128_core(qb, wqb, blockIdx.x * 128, blockIdx.y * 128, As, Bs,
                     [&](int m, int n, float v) {
            const int b = m >> 10, q = m & 1023;
            const int h = n >> 6,  d = n & 63;
            qp[(((size_t)(b * 16 + h) * NQ_ + q) << 6) + d] = (__bf16)v;
        });
    } else if (z == 1) {
        gemm128_core(kb, wkb, blockIdx.x * 128, blockIdx.y * 128, As, Bs,
                     [&](int m, int n, float v) {
            const int b = m >> 11, key = m & 2047;
            const int h = n >> 6,  d = n & 63;
            kp[(((size_t)(b * 16 + h) * NK_ + key) << 6) + d] = (__bf16)v;
        });
    } else {
        // swapped: A = Wv (rows = hd), B = V (rows = keys)
        gemm128_core(wvb, vb, blockIdx.y * 128, blockIdx.x * 128, As, Bs,
                     [&](int m, int n, float v) {
            const int h = m >> 6,  d = m & 63;
            const int b = n >> 11, key = n & 2047;
            vpT[((size_t)(b * 16 + h) * HD_ + d) * VPAD + key] = (__bf16)v;
        });
    }
}

// Output projection: attnout(2048x1024 bf16) x Wo^T -> d_out f32
__global__ __launch_bounds__(256) void oproj_kernel(
    const __bf16* __restrict__ A, const __bf16* __restrict__ W,
    float* __restrict__ Cout)
{
    const int m0 = blockIdx.x * 32, n0 = blockIdx.y * 128;
    gemm32_core(A, W, m0, n0, [&](int m, int n, float v) {
        Cout[(size_t)m * 1024 + n] = v;
    });
}

// ---------------------------------------------------------------------------
// Fused attention (R9-proven form), full key range per block, combine fused:
// block = 4 waves x 16 q-rows = 64 q, one bh. Software-pipelined PV(i-1)
// between QK(i) MFMAs and exp(i) VALU. Gate folded into the exponent:
// eg = exp(s/8 + c*d), c = -softplus(a)/mean, masked d = 3e38 -> exp = 0.
// Epilogue normalizes by complete G, applies kpm_q, writes attnout bf16.
// ---------------------------------------------------------------------------
__global__ __launch_bounds__(256, 2) void attn_kernel(
    const __bf16* __restrict__ qp, const __bf16* __restrict__ kp,
    const __bf16* __restrict__ vpT, const __bf16* __restrict__ dmask,
    const float* __restrict__ msum, const float* __restrict__ galpha,
    const int* __restrict__ kpmq, __bf16* __restrict__ attnout)
{
    __shared__ __bf16 Ks[64 * 72];
    __shared__ __bf16 Vt[2][64 * 72];
    __shared__ __bf16 Ps[4][2][16 * 72];
    const int t    = threadIdx.x;
    const int w    = t >> 6, lane = t & 63;
    const int lrow = lane & 15, quad = lane >> 4;
    const int qt   = blockIdx.x;          // 0..15
    const int bh   = blockIdx.y;          // 0..31
    const int b    = bh >> 4, h = bh & 15;
    const int q0   = qt * 64 + w * 16;
    const int NT   = NK_ / 64;            // 32 tiles

    const float mean  = fmaxf(msum[b] / ((float)(NQ_ * NK_) + 1e-6f), 1e-6f);
    const float alpha = log1pf(__expf(galpha[0]));
    const float cg    = -alpha / mean;    // strictly negative

    const __bf16* qb = qp + ((size_t)bh * NQ_ + q0 + lrow) * HD_ + quad * 8;
    const bf16x8 qf0 = *(const bf16x8*)qb;
    const bf16x8 qf1 = *(const bf16x8*)(qb + 32);

    const int srow0 = t >> 3,        sc0 = t & 7;
    const int srow1 = 32 + (t >> 3), sc1 = t & 7;
    const int so0 = srow0 * 72 + sc0 * 8;
    const int so1 = srow1 * 72 + sc1 * 8;
    const __bf16* Kg = kp  + (size_t)bh * NK_ * HD_;
    const __bf16* Vg = vpT + (size_t)bh * HD_ * VPAD;
    const __bf16* grow = dmask + ((size_t)b * NQ_ + q0 + lrow) * GPAD;

    float G = 0.f;
    floatx4 O[4];
    #pragma unroll
    for (int nb = 0; nb < 4; nb++) O[nb] = floatx4{0.f, 0.f, 0.f, 0.f};

    bf16x8 kr0, kr1, vr0, vr1;
    bf16x4 gr[4];
    auto loadt = [&](int kb) {
        kr0 = *(const bf16x8*)(Kg + (size_t)(kb + srow0) * HD_ + sc0 * 8);
        kr1 = *(const bf16x8*)(Kg + (size_t)(kb + srow1) * HD_ + sc1 * 8);
        vr0 = *(const bf16x8*)(Vg + (size_t)srow0 * VPAD + kb + sc0 * 8);
        vr1 = *(const bf16x8*)(Vg + (size_t)srow1 * VPAD + kb + sc1 * 8);
        #pragma unroll
        for (int c = 0; c < 4; c++)
            gr[c] = *(const bf16x4*)(grow + kb + c * 16 + quad * 4);
    };
    loadt(0);

    for (int ib = 0; ib < NT; ib++) {
        const int kb  = ib * 64;
        const int cur = ib & 1;

        __syncthreads();                  // prior Ks / Vt[cur] reads complete
        *(bf16x8*)&Ks[so0]      = kr0;
        *(bf16x8*)&Ks[so1]      = kr1;
        *(bf16x8*)&Vt[cur][so0] = vr0;
        *(bf16x8*)&Vt[cur][so1] = vr1;
        __syncthreads();                  // staging visible

        bf16x4 gcur[4];
        #pragma unroll
        for (int c = 0; c < 4; c++) gcur[c] = gr[c];
        if (ib + 1 < NT) loadt(kb + 64);

        // --- QK(i) ---
        floatx4 s4[4];
        #pragma unroll
        for (int c = 0; c < 4; c++) {
            bf16x8 kf0 = *(const bf16x8*)&Ks[(c * 16 + lrow) * 72 + quad * 8];
            bf16x8 kf1 = *(const bf16x8*)&Ks[(c * 16 + lrow) * 72 + 32 + quad * 8];
            floatx4 a = floatx4{0.f, 0.f, 0.f, 0.f};
            a = mfma16(kf0, qf0, a);
            a = mfma16(kf1, qf1, a);
            s4[c] = a;
        }

        // --- PV(i-1): independent of s4 -> fills the wait on QK results ---
        if (ib > 0) {
            const int prv = cur ^ 1;
            bf16x8 pf0 = *(const bf16x8*)&Ps[w][prv][lrow * 72 + quad * 8];
            bf16x8 pf1 = *(const bf16x8*)&Ps[w][prv][lrow * 72 + 32 + quad * 8];
            #pragma unroll
            for (int nb = 0; nb < 4; nb++) {
                bf16x8 vf0 = *(const bf16x8*)
                    &Vt[prv][(nb * 16 + lrow) * 72 + quad * 8];
                bf16x8 vf1 = *(const bf16x8*)
                    &Vt[prv][(nb * 16 + lrow) * 72 + 32 + quad * 8];
                O[nb] = mfma16(pf0, vf0, O[nb]);
                O[nb] = mfma16(pf1, vf1, O[nb]);
            }
        }

        // --- exp(i): eg = exp(s/8 + c*d) -> Ps[cur] ---
        #pragma unroll
        for (int c = 0; c < 4; c++) {
            const float e0 = __expf(fmaf(s4[c][0], 0.125f, cg * (float)gcur[c][0]));
            const float e1 = __expf(fmaf(s4[c][1], 0.125f, cg * (float)gcur[c][1]));
            const float e2 = __expf(fmaf(s4[c][2], 0.125f, cg * (float)gcur[c][2]));
            const float e3 = __expf(fmaf(s4[c][3], 0.125f, cg * (float)gcur[c][3]));
            G += (e0 + e1) + (e2 + e3);
            bf16x4 pk;
            pk[0] = (__bf16)e0; pk[1] = (__bf16)e1;
            pk[2] = (__bf16)e2; pk[3] = (__bf16)e3;
            *(bf16x4*)&Ps[w][cur][lrow * 72 + c * 16 + quad * 4] = pk;
        }
    }

    // --- final PV(NT-1) ---
    {
        const int prv = (NT - 1) & 1;
        bf16x8 pf0 = *(const bf16x8*)&Ps[w][prv][lrow * 72 + quad * 8];
        bf16x8 pf1 = *(const bf16x8*)&Ps[w][prv][lrow * 72 + 32 + quad * 8];
        #pragma unroll
        for (int nb = 0; nb < 4; nb++) {
            bf16x8 vf0 = *(const bf16x8*)&Vt[prv][(nb * 16 + lrow) * 72 + quad * 8];
            bf16x8 vf1 = *(const bf16x8*)&Vt[prv][(nb * 16 + lrow) * 72 + 32 + quad * 8];
            O[nb] = mfma16(pf0, vf0, O[nb]);
            O[nb] = mfma16(pf1, vf1, O[nb]);
        }
    }

    // G complete (full key range): reduce across quads, broadcast per row.
    G += __shfl_xor(G, 16);
    G += __shfl_xor(G, 32);               // lanes 0..15 hold G for q = q0+lrow

    #pragma unroll
    for (int r = 0; r < 4; r++) {
        const int q  = q0 + quad * 4 + r;
        const float gq = __shfl(G, quad * 4 + r);
        const float f  = kpmq[b * NQ_ + q] ? 1.f / (gq + 1e-30f) : 0.f;
        #pragma unroll
        for (int nb = 0; nb < 4; nb++) {
            attnout[((size_t)b * NQ_ + q) * 1024 + h * HD_ + nb * 16 + lrow] =
                (__bf16)(O[nb][r] * f);
        }
    }
}

// ---------------------------------------------------------------------------
extern "C" void kernel_launch(void* const* d_in, const int* in_sizes, int n_in,
                              void* d_out, int out_size, void* d_ws,
                              size_t ws_size, hipStream_t stream)
{
    const float* q      = (const float*)d_in[0];
    const float* k      = (const float*)d_in[1];
    const float* v      = (const float*)d_in[2];
    const float* dist   = (const float*)d_in[3];
    const int*   amask  = (const int*)d_in[4];
    const int*   kpmq   = (const int*)d_in[5];
    const int*   kpmk   = (const int*)d_in[6];
    const float* Wq     = (const float*)d_in[7];
    const float* Wk     = (const float*)d_in[8];
    const float* Wv     = (const float*)d_in[9];
    const float* Wo     = (const float*)d_in[10];
    const float* galpha = (const float*)d_in[11];

    char* p = (char*)d_ws;
    float*  msum = (float*)p;                 p += 256;
    __bf16* qb   = (__bf16*)p;                p += (size_t)2097152 * 2;
    __bf16* kb   = (__bf16*)p;                p += (size_t)4194304 * 2;
    __bf16* vb   = (__bf16*)p;                p += (size_t)4194304 * 2;
    __bf16* wqb  = (__bf16*)p;                p += (size_t)1048576 * 2;
    __bf16* wkb  = (__bf16*)p;                p += (size_t)1048576 * 2;
    __bf16* wvb  = (__bf16*)p;                p += (size_t)1048576 * 2;
    __bf16* wob  = (__bf16*)p;                p += (size_t)1048576 * 2;
    __bf16* qp   = (__bf16*)p;                p += (size_t)2097152 * 2;
    __bf16* kpb  = (__bf16*)p;                p += (size_t)4194304 * 2;
    __bf16* vpT  = (__bf16*)p;                p += (size_t)32 * 64 * VPAD * 2;
    __bf16* dmask = (__bf16*)p;               p += (size_t)2048 * GPAD * 2;
    __bf16* attnout = (__bf16*)p;             p += (size_t)2097152 * 2;

    CvtArgs ca;
    ca.src[0] = q;  ca.src[1] = k;  ca.src[2] = v;
    ca.src[3] = Wq; ca.src[4] = Wk; ca.src[5] = Wv; ca.src[6] = Wo;
    ca.dst[0] = qb;  ca.dst[1] = kb;  ca.dst[2] = vb;
    ca.dst[3] = wqb; ca.dst[4] = wkb; ca.dst[5] = wvb; ca.dst[6] = wob;

    hipMemsetAsync(msum, 0, 256, stream);
    cvt_mean_kernel<<<2816, 256, 0, stream>>>(ca, dist, amask, kpmk, msum,
                                              dmask);
    proj_kernel<<<dim3(32, 8, 3), 256, 0, stream>>>(qb, kb, vb, wqb, wkb, wvb,
                                                    qp, kpb, vpT);
    attn_kernel<<<dim3(16, 32), 256, 0, stream>>>(qp, kpb, vpT, dmask,
                                                  msum, galpha, kpmq, attnout);
    oproj_kernel<<<dim3(64, 8), 256, 0, stream>>>(attnout, wob, (float*)d_out);
}